// Round 7
// baseline (153.596 us; speedup 1.0000x reference)
//
#include <hip/hip_runtime.h>
#include <hip/hip_bf16.h>

#define BB 64
#define TT 16
#define ROWS 1024
#define ADIM 32
#define HID 1536
#define NCAT 4
#define MT_MAX 20            // worst case sum ceil(cnt_c/4) = 19
#define NTILE 24             // HID/64 n-tiles
#define GRID_G (MT_MAX * NTILE)   // 480 = 8 * 60

typedef __attribute__((ext_vector_type(8))) short bf16x8;
typedef __attribute__((ext_vector_type(4))) float f32x4;

static __device__ __forceinline__ unsigned short f2bf(float f) {
    union { float f; unsigned int u; } v; v.f = f;
    unsigned int u = v.u + 0x7fff + ((v.u >> 16) & 1);   // RNE
    return (unsigned short)(u >> 16);
}
static __device__ __forceinline__ short f2bf_s(float f) {
    __hip_bfloat16 h = __float2bfloat16(f);
    return __builtin_bit_cast(short, h);
}

// ---------------------------------------------------------------------------
// prep: group samples by category into padded 4-sample m-tiles.
// ---------------------------------------------------------------------------
__global__ void prep_kernel(const int* __restrict__ cat_ids,
                            int* __restrict__ msample, int* __restrict__ mcat) {
    __shared__ int counts[NCAT];
    const int t = threadIdx.x;
    if (t < NCAT) {
        int c = 0;
        for (int s = 0; s < BB; ++s) c += (cat_ids[s] == t);
        counts[t] = c;
    }
    __syncthreads();
    if (t < NCAT) {
        int off = 0;
        for (int c = 0; c < t; ++c) off += (counts[c] + 3) >> 2;
        const int mt = (counts[t] + 3) >> 2;
        int idx = 0;
        for (int s = 0; s < BB; ++s)
            if (cat_ids[s] == t) msample[off * 4 + (idx++)] = s;
        for (; idx < mt * 4; ++idx) msample[off * 4 + idx] = -1;
        for (int mm = 0; mm < mt; ++mm) mcat[off + mm] = t;
    }
    __syncthreads();
    if (t == 0) {
        int tot = 0;
        for (int c = 0; c < NCAT; ++c) tot += (counts[c] + 3) >> 2;
        for (int mm = tot; mm < MT_MAX; ++mm) mcat[mm] = -1;
    }
}

// ---------------------------------------------------------------------------
// build_x: X[row][0:1536] = actions @ W1[cat] + b1[cat]; X[row][1536:3072] = PE
// ---------------------------------------------------------------------------
__global__ void build_x_kernel(const float* __restrict__ actions,
                               const int* __restrict__ timesteps,
                               const int* __restrict__ cat_ids,
                               const float* __restrict__ W1,
                               const float* __restrict__ b1,
                               unsigned short* __restrict__ X) {
    const int s = blockIdx.x;
    const int part = blockIdx.y;
    const int t = threadIdx.x;
    if (part < 6) {
        const int cat = cat_ids[s];
        const int h = part * 256 + t;
        __shared__ float act[TT][ADIM];
        const float* ab = actions + (size_t)s * TT * ADIM;
        ((float*)act)[t]       = ab[t];
        ((float*)act)[t + 256] = ab[t + 256];
        __syncthreads();
        const float* W1c = W1 + (size_t)cat * ADIM * HID + h;
        float acc[TT];
        #pragma unroll
        for (int r = 0; r < TT; ++r) acc[r] = 0.f;
        #pragma unroll 8
        for (int d = 0; d < ADIM; ++d) {
            const float wv = W1c[(size_t)d * HID];
            #pragma unroll
            for (int r = 0; r < TT; ++r) acc[r] += act[r][d] * wv;
        }
        const float bias = b1[cat * HID + h];
        #pragma unroll
        for (int r = 0; r < TT; ++r)
            X[(size_t)(s * TT + r) * (2 * HID) + h] = f2bf(acc[r] + bias);
    } else {
        const float ts = (float)timesteps[s];
        #pragma unroll
        for (int j = 0; j < 6; ++j) {
            const int i = j * 256 + t;
            const int ii = (i < 768) ? i : i - 768;
            const float freq = expf(-9.210340371976184f * (float)ii * (1.0f / 768.0f));
            const float ang = ts * freq;
            const float v = (i < 768) ? sinf(ang) : cosf(ang);
            const unsigned short bv = f2bf(v);
            for (int r = 0; r < TT; ++r)
                X[(size_t)(s * TT + r) * (2 * HID) + HID + i] = bv;
        }
    }
}

// ---------------------------------------------------------------------------
// gemm_gll: single-wave 64x64 tile, full K, fused bias(+swish).
//   A and B staged via global_load_lds into wave-private triple-buffered LDS,
//   hand-counted vmcnt (no barriers -> no drain). 12 gll insts / K-step:
//     A: 4 x dwordx4 -> Alds[ib][p][64 rows][8 bf16]   (R2-measured conflict-free)
//     B: 8 x dwordx4 -> Blds[ib][j][g*64 + col*4] fp32 (264-dword j-stride: 2-way banks)
// ---------------------------------------------------------------------------
template<int K, bool SWISH, bool BF16OUT>
__global__ __launch_bounds__(64) void gemm_gll(
        const unsigned short* __restrict__ Xin,  // [ROWS][K] bf16
        const float* __restrict__ W,             // [NCAT][K][HID] fp32
        const float* __restrict__ bias,          // [NCAT][HID]
        const int* __restrict__ msample,
        const int* __restrict__ mcat,
        void* __restrict__ Out) {
    constexpr int NT = K / 32;

    // XCD swizzle, nt-major per XCD: same W n-slice reused by the m-tiles on one XCD
    const int id   = blockIdx.x;
    const int g480 = (id & 7) * (GRID_G / 8) + (id >> 3);
    const int nt   = g480 / MT_MAX;
    const int m    = g480 - nt * MT_MAX;
    const int cat  = mcat[m];
    if (cat < 0) return;
    const int n0 = nt * 64;

    const int l   = threadIdx.x;
    const int col = l & 15;
    const int g   = l >> 4;

    int sidx[4];
    #pragma unroll
    for (int f = 0; f < 4; ++f) sidx[f] = msample[m * 4 + f];

    __shared__ unsigned short Alds[3][4][64][8];   // 12,288 B
    __shared__ float          Blds[3][8][264];     // 25,344 B (264-dword inst stride)

    // per-lane global sources; p-slot offset baked into the pointer (offset arg
    // of global_load_lds must be a literal)
    const int sA = (sidx[g] < 0) ? 0 : sidx[g];    // tile row = lane l: sample g, trow col
    const unsigned short* aPtr[4];
    #pragma unroll
    for (int p = 0; p < 4; ++p)
        aPtr[p] = Xin + ((size_t)sA * TT + col) * K + p * 8;
    const float* bPtr[8];
    #pragma unroll
    for (int j = 0; j < 8; ++j)
        bPtr[j] = W + ((size_t)cat * K + 4 * j + g) * HID + n0 + col * 4;

    f32x4 acc[4][4];
    #pragma unroll
    for (int i = 0; i < 4; ++i)
        #pragma unroll
        for (int j = 0; j < 4; ++j) acc[i][j] = f32x4{0.f, 0.f, 0.f, 0.f};

    auto ISSUE = [&](int ib) {
        #pragma unroll
        for (int p = 0; p < 4; ++p) {
            __builtin_amdgcn_global_load_lds(
                (const __attribute__((address_space(1))) unsigned int*)(aPtr[p]),
                (__attribute__((address_space(3))) unsigned int*)(&Alds[ib][p][0][0]),
                16, 0, 0);
            aPtr[p] += 32;                           // next K-step
        }
        #pragma unroll
        for (int j = 0; j < 8; ++j) {
            __builtin_amdgcn_global_load_lds(
                (const __attribute__((address_space(1))) unsigned int*)(bPtr[j]),
                (__attribute__((address_space(3))) unsigned int*)(&Blds[ib][j][0]),
                16, 0, 0);
            bPtr[j] += (size_t)32 * HID;
        }
    };

    auto COMPUTE = [&](int ib) {
        bf16x8 afr[4];
        #pragma unroll
        for (int mf = 0; mf < 4; ++mf)
            afr[mf] = *(const bf16x8*)(&Alds[ib][g][mf * 16 + col][0]);
        #pragma unroll
        for (int nf = 0; nf < 4; ++nf) {
            bf16x8 bb;
            #pragma unroll
            for (int e = 0; e < 8; ++e)
                bb[e] = f2bf_s(Blds[ib][2 * g + (e >> 2)][(e & 3) * 64 + nf * 16 + col]);
            #pragma unroll
            for (int mf = 0; mf < 4; ++mf)
                acc[mf][nf] = __builtin_amdgcn_mfma_f32_16x16x32_bf16(
                    afr[mf], bb, acc[mf][nf], 0, 0, 0);
        }
    };

    // prologue: stages 0,1 in flight (24 outstanding vmem ops)
    ISSUE(0);
    ISSUE(1);
    int ibC = 0;
    for (int t = 0; t < NT - 2; ++t) {
        ISSUE(ibC == 0 ? 2 : ibC - 1);               // buffer (t+2)%3
        asm volatile("s_waitcnt vmcnt(24)" ::: "memory");   // stage t landed
        COMPUTE(ibC);
        ibC = (ibC == 2) ? 0 : ibC + 1;
    }
    asm volatile("s_waitcnt vmcnt(12)" ::: "memory");
    COMPUTE(ibC);
    ibC = (ibC == 2) ? 0 : ibC + 1;
    asm volatile("s_waitcnt vmcnt(0)" ::: "memory");
    COMPUTE(ibC);

    // fused epilogue: bias (+swish), direct store. D row = g*4+r, col = l&15.
    const float* bc = bias + (size_t)cat * HID + n0 + col;
    #pragma unroll
    for (int mf = 0; mf < 4; ++mf) {
        if (sidx[mf] < 0) continue;
        const size_t rowbase = (size_t)sidx[mf] * TT + g * 4;
        #pragma unroll
        for (int nf = 0; nf < 4; ++nf) {
            const float bv = bc[nf * 16];
            #pragma unroll
            for (int r = 0; r < 4; ++r) {
                float v = acc[mf][nf][r] + bv;
                if (SWISH) v = v / (1.f + __expf(-v));
                const size_t off = (rowbase + r) * HID + n0 + nf * 16 + col;
                if (BF16OUT) ((unsigned short*)Out)[off] = f2bf(v);
                else         ((float*)Out)[off] = v;
            }
        }
    }
}

// ---------------------------------------------------------------------------
extern "C" void kernel_launch(void* const* d_in, const int* in_sizes, int n_in,
                              void* d_out, int out_size, void* d_ws, size_t ws_size,
                              hipStream_t stream) {
    const float* actions   = (const float*)d_in[0];
    const int*   timesteps = (const int*)d_in[1];
    const int*   cat_ids   = (const int*)d_in[2];
    const float* W1        = (const float*)d_in[3];
    const float* b1        = (const float*)d_in[4];
    const float* W2        = (const float*)d_in[5];
    const float* b2        = (const float*)d_in[6];
    const float* W3        = (const float*)d_in[7];
    const float* b3        = (const float*)d_in[8];

    char* ws = (char*)d_ws;
    unsigned short* X = (unsigned short*)ws;                 // 6,291,456 B
    unsigned short* H = (unsigned short*)(ws + 6291456);     // 3,145,728 B
    int* msample      = (int*)(ws + 9437184);
    int* mcat         = msample + MT_MAX * 4;

    prep_kernel<<<1, 64, 0, stream>>>(cat_ids, msample, mcat);
    build_x_kernel<<<dim3(BB, 7), 256, 0, stream>>>(actions, timesteps, cat_ids, W1, b1, X);

    gemm_gll<2 * HID, true, true><<<GRID_G, 64, 0, stream>>>(
        X, W2, b2, msample, mcat, H);
    gemm_gll<HID, false, false><<<GRID_G, 64, 0, stream>>>(
        H, W3, b3, msample, mcat, d_out);
}

// Round 9
// 147.014 us; speedup vs baseline: 1.0448x; 1.0448x over previous
//
#include <hip/hip_runtime.h>
#include <hip/hip_bf16.h>

#define BB 64
#define TT 16
#define ROWS 1024
#define ADIM 32
#define HID 1536
#define NCAT 4
#define MT_MAX 20            // worst case sum ceil(cnt_c/4) = 19
#define NTILE 24             // HID/64 n-tiles
#define GRID_G (MT_MAX * NTILE)   // 480 = 8 * 60

typedef __attribute__((ext_vector_type(8))) short bf16x8;
typedef __attribute__((ext_vector_type(4))) float f32x4;

static __device__ __forceinline__ unsigned short fb(float f) {
    return __builtin_bit_cast(unsigned short, __float2bfloat16(f));
}
static __device__ __forceinline__ unsigned pk2(float lo, float hi) {
    return (unsigned)fb(lo) | ((unsigned)fb(hi) << 16);
}
// per-32 k-permutation: original offset o lives at position q(o) = (o&3)*8 + (o>>2).
// Frag position q = g*8+e then holds original k-offset 4e+g.
static __device__ __forceinline__ int qperm(int o) { return (o & 3) * 8 + (o >> 2); }

// ---------------------------------------------------------------------------
// prep: group samples by category into padded 4-sample m-tiles.
// ---------------------------------------------------------------------------
__global__ void prep_kernel(const int* __restrict__ cat_ids,
                            int* __restrict__ msample, int* __restrict__ mcat) {
    __shared__ int counts[NCAT];
    const int t = threadIdx.x;
    if (t < NCAT) {
        int c = 0;
        for (int s = 0; s < BB; ++s) c += (cat_ids[s] == t);
        counts[t] = c;
    }
    __syncthreads();
    if (t < NCAT) {
        int off = 0;
        for (int c = 0; c < t; ++c) off += (counts[c] + 3) >> 2;
        const int mt = (counts[t] + 3) >> 2;
        int idx = 0;
        for (int s = 0; s < BB; ++s)
            if (cat_ids[s] == t) msample[off * 4 + (idx++)] = s;
        for (; idx < mt * 4; ++idx) msample[off * 4 + idx] = -1;
        for (int mm = 0; mm < mt; ++mm) mcat[off + mm] = t;
    }
    __syncthreads();
    if (t == 0) {
        int tot = 0;
        for (int c = 0; c < NCAT; ++c) tot += (counts[c] + 3) >> 2;
        for (int mm = tot; mm < MT_MAX; ++mm) mcat[mm] = -1;
    }
}

// ---------------------------------------------------------------------------
// build_x: X'[row] = perm(concat(actions@W1[cat]+b1, PE)) as bf16, stride 3072.
// Stores go to position (k & ~31) + qperm(k & 31).
// ---------------------------------------------------------------------------
__global__ void build_x_kernel(const float* __restrict__ actions,
                               const int* __restrict__ timesteps,
                               const int* __restrict__ cat_ids,
                               const float* __restrict__ W1,
                               const float* __restrict__ b1,
                               unsigned short* __restrict__ X) {
    const int s = blockIdx.x;
    const int part = blockIdx.y;
    const int t = threadIdx.x;
    if (part < 6) {
        const int cat = cat_ids[s];
        const int h = part * 256 + t;
        __shared__ float act[TT][ADIM];
        const float* ab = actions + (size_t)s * TT * ADIM;
        ((float*)act)[t]       = ab[t];
        ((float*)act)[t + 256] = ab[t + 256];
        __syncthreads();
        const float* W1c = W1 + (size_t)cat * ADIM * HID + h;
        float acc[TT];
        #pragma unroll
        for (int r = 0; r < TT; ++r) acc[r] = 0.f;
        #pragma unroll 8
        for (int d = 0; d < ADIM; ++d) {
            const float wv = W1c[(size_t)d * HID];
            #pragma unroll
            for (int r = 0; r < TT; ++r) acc[r] += act[r][d] * wv;
        }
        const float bias = b1[cat * HID + h];
        const int pos = (h & ~31) + qperm(h & 31);
        #pragma unroll
        for (int r = 0; r < TT; ++r)
            X[(size_t)(s * TT + r) * (2 * HID) + pos] = fb(acc[r] + bias);
    } else {
        const float ts = (float)timesteps[s];
        #pragma unroll
        for (int j = 0; j < 6; ++j) {
            const int i = j * 256 + t;
            const int ii = (i < 768) ? i : i - 768;
            const float freq = expf(-9.210340371976184f * (float)ii * (1.0f / 768.0f));
            const float ang = ts * freq;
            const float v = (i < 768) ? sinf(ang) : cosf(ang);
            const unsigned short bv = fb(v);
            const int pos = HID + (i & ~31) + qperm(i & 31);
            for (int r = 0; r < TT; ++r)
                X[(size_t)(s * TT + r) * (2 * HID) + pos] = bv;
        }
    }
}

// ---------------------------------------------------------------------------
// gemm_v8: 64x64 tile, 4 waves, in-block K-split (wave w owns K/4), full fuse.
//   B: 8 coalesced float4 loads (2-stage reg prefetch, counted vmcnt) ->
//      cvt bf16 -> 4x ds_write_b128 into img[n][g][8] (80B rows, conflict-free)
//      -> 4x ds_read_b128 frags. k within each 32-block is permuted by qperm
//      on BOTH operands (identical permutation => identical MFMA result).
//   A: X'/H' (already permuted) global->reg bf16x8, 2-stage.
//   No barriers in K-loop; end: LDS reduce across waves + bias(+swish) store.
// ---------------------------------------------------------------------------
template<int K, bool SWISH, bool PERMOUT>
__global__ __launch_bounds__(256) void gemm_v8(
        const unsigned short* __restrict__ Xin,  // [ROWS][K] bf16 (permuted)
        const float* __restrict__ W,             // [NCAT][K][HID] fp32
        const float* __restrict__ bias,          // [NCAT][HID]
        const int* __restrict__ msample,
        const int* __restrict__ mcat,
        void* __restrict__ Out) {
    constexpr int KP = K / 4;
    constexpr int NT = KP / 32;
    static_assert(NT % 2 == 0, "NT must be even");

    // bijective XCD swizzle (480 % 8 == 0), nt-major per XCD (B-panel L2 reuse)
    const int id = blockIdx.x;
    const int gg = (id & 7) * (GRID_G / 8) + (id >> 3);
    const int nt = gg / MT_MAX;
    const int m  = gg - nt * MT_MAX;
    const int cat = mcat[m];
    if (cat < 0) return;
    const int n0 = nt * 64;

    const int q   = threadIdx.x;
    const int w   = q >> 6;                 // wave id = k-slice
    const int l   = q & 63;
    const int col = l & 15, g  = l >> 4;    // compute-role decomposition
    const int c2  = l >> 2,  g2 = l & 3;    // stage-role decomposition
    const int k0  = w * KP;

    int sidx[4];
    #pragma unroll
    for (int f = 0; f < 4; ++f) sidx[f] = msample[m * 4 + f];

    // LDS: per-wave transpose image img[64 n][40 ushort] (80B rows), aliased
    // with the cross-wave reduce scratch R[4][3][16][65] f32 (49,920 B).
    __shared__ __align__(16) char smem[49920];
    unsigned short* img = (unsigned short*)smem + (size_t)w * 64 * 40;
    float (*R)[3][16][65] = reinterpret_cast<float(*)[3][16][65]>(smem);

    // A bases: frag lane (col,g) reads X'[sample*16+col][k0 + t*32 + g*8 .. +8]
    const unsigned short* aB[4];
    #pragma unroll
    for (int mf = 0; mf < 4; ++mf) {
        const int s = sidx[mf] < 0 ? 0 : sidx[mf];
        aB[mf] = Xin + ((size_t)s * TT + col) * K + k0 + g * 8;
    }
    // B base: stage lane (c2,g2), inst j: W[k0 + t*32 + 4j + g2][n0 + 4*c2 .. +3]
    const float* bB = W + ((size_t)cat * K + k0 + g2) * HID + n0 + c2 * 4;

    f32x4 acc[4][4];
    #pragma unroll
    for (int i = 0; i < 4; ++i)
        #pragma unroll
        for (int j = 0; j < 4; ++j) acc[i][j] = f32x4{0.f, 0.f, 0.f, 0.f};

    float4 bg0[8], bg1[8];
    bf16x8 a0[4], a1[4];

    auto loadStage = [&](int t, float4 (&bg)[8], bf16x8 (&a)[4]) {
        const float* wp = bB + (size_t)t * 32 * HID;
        #pragma unroll
        for (int j = 0; j < 8; ++j)
            bg[j] = *(const float4*)(wp + (size_t)(4 * j) * HID);
        #pragma unroll
        for (int mf = 0; mf < 4; ++mf)
            a[mf] = *(const bf16x8*)(aB[mf] + t * 32);
    };

    auto consume = [&](float4 (&bg)[8], bf16x8 (&a)[4]) {
        // transpose via LDS: stage lane writes, for each of its 4 n's, the
        // 8 bf16 k-run (j=0..7 -> frag elems e=0..7) as one b128.
        #pragma unroll
        for (int i = 0; i < 4; ++i) {
            uint4 v;
            float e0, e1, e2, e3, e4, e5, e6, e7;
            if (i == 0) { e0=bg[0].x; e1=bg[1].x; e2=bg[2].x; e3=bg[3].x; e4=bg[4].x; e5=bg[5].x; e6=bg[6].x; e7=bg[7].x; }
            if (i == 1) { e0=bg[0].y; e1=bg[1].y; e2=bg[2].y; e3=bg[3].y; e4=bg[4].y; e5=bg[5].y; e6=bg[6].y; e7=bg[7].y; }
            if (i == 2) { e0=bg[0].z; e1=bg[1].z; e2=bg[2].z; e3=bg[3].z; e4=bg[4].z; e5=bg[5].z; e6=bg[6].z; e7=bg[7].z; }
            if (i == 3) { e0=bg[0].w; e1=bg[1].w; e2=bg[2].w; e3=bg[3].w; e4=bg[4].w; e5=bg[5].w; e6=bg[6].w; e7=bg[7].w; }
            v.x = pk2(e0, e1); v.y = pk2(e2, e3); v.z = pk2(e4, e5); v.w = pk2(e6, e7);
            *(uint4*)(img + (size_t)(c2 * 4 + i) * 40 + g2 * 8) = v;
        }
        // frag reads: lane (col,g), frag nf -> img[nf*16+col][g*8..]
        bf16x8 bf[4];
        #pragma unroll
        for (int nf = 0; nf < 4; ++nf)
            bf[nf] = *(const bf16x8*)(img + (size_t)(nf * 16 + col) * 40 + g * 8);
        asm volatile("s_waitcnt lgkmcnt(0)" ::: "memory");
        __builtin_amdgcn_sched_barrier(0);
        #pragma unroll
        for (int mf = 0; mf < 4; ++mf)
            #pragma unroll
            for (int nf = 0; nf < 4; ++nf)
                acc[mf][nf] = __builtin_amdgcn_mfma_f32_16x16x32_bf16(
                    a[mf], bf[nf], acc[mf][nf], 0, 0, 0);
    };

    // 2-stage pipeline, counted vmcnt (12 loads per stage), no barriers
    loadStage(0, bg0, a0);
    for (int t = 0; t < NT - 2; t += 2) {
        loadStage(t + 1, bg1, a1);
        asm volatile("s_waitcnt vmcnt(12)" ::: "memory");
        consume(bg0, a0);
        loadStage(t + 2, bg0, a0);
        asm volatile("s_waitcnt vmcnt(12)" ::: "memory");
        consume(bg1, a1);
    }
    loadStage(NT - 1, bg1, a1);
    asm volatile("s_waitcnt vmcnt(12)" ::: "memory");
    consume(bg0, a0);
    asm volatile("s_waitcnt vmcnt(0)" ::: "memory");
    consume(bg1, a1);

    // -------- cross-wave k-slice reduce + fused epilogue --------
    __syncthreads();
    #pragma unroll
    for (int mf = 0; mf < 4; ++mf) {
        if (mf == w) continue;
        const int slot = w - (w > mf ? 1 : 0);
        #pragma unroll
        for (int nf = 0; nf < 4; ++nf)
            #pragma unroll
            for (int jj = 0; jj < 4; ++jj)
                R[mf][slot][g * 4 + jj][nf * 16 + col] = acc[mf][nf][jj];
    }
    __syncthreads();

    if (sidx[w] >= 0) {
        const float* bc = bias + (size_t)cat * HID + n0 + col;
        #pragma unroll
        for (int nf = 0; nf < 4; ++nf) {
            const float bv = bc[nf * 16];
            const int n = n0 + nf * 16 + col;
            #pragma unroll
            for (int jj = 0; jj < 4; ++jj) {
                float v = acc[w][nf][jj]
                        + R[w][0][g * 4 + jj][nf * 16 + col]
                        + R[w][1][g * 4 + jj][nf * 16 + col]
                        + R[w][2][g * 4 + jj][nf * 16 + col]
                        + bv;
                if (SWISH) v = v / (1.f + __expf(-v));
                const size_t row = (size_t)sidx[w] * TT + g * 4 + jj;
                if (PERMOUT) {
                    const size_t off = row * HID + (n & ~31) + qperm(n & 31);
                    ((unsigned short*)Out)[off] = fb(v);
                } else {
                    ((float*)Out)[row * HID + n] = v;
                }
            }
        }
    }
}

// ---------------------------------------------------------------------------
extern "C" void kernel_launch(void* const* d_in, const int* in_sizes, int n_in,
                              void* d_out, int out_size, void* d_ws, size_t ws_size,
                              hipStream_t stream) {
    const float* actions   = (const float*)d_in[0];
    const int*   timesteps = (const int*)d_in[1];
    const int*   cat_ids   = (const int*)d_in[2];
    const float* W1        = (const float*)d_in[3];
    const float* b1        = (const float*)d_in[4];
    const float* W2        = (const float*)d_in[5];
    const float* b2        = (const float*)d_in[6];
    const float* W3        = (const float*)d_in[7];
    const float* b3        = (const float*)d_in[8];

    char* ws = (char*)d_ws;
    unsigned short* X = (unsigned short*)ws;                 // 6,291,456 B (permuted bf16)
    unsigned short* H = (unsigned short*)(ws + 6291456);     // 3,145,728 B (permuted bf16)
    int* msample      = (int*)(ws + 9437184);
    int* mcat         = msample + MT_MAX * 4;

    prep_kernel<<<1, 64, 0, stream>>>(cat_ids, msample, mcat);
    build_x_kernel<<<dim3(BB, 7), 256, 0, stream>>>(actions, timesteps, cat_ids, W1, b1, X);

    gemm_v8<2 * HID, true, true><<<GRID_G, 256, 0, stream>>>(
        X, W2, b2, msample, mcat, H);
    gemm_v8<HID, false, false><<<GRID_G, 256, 0, stream>>>(
        H, W3, b3, msample, mcat, d_out);
}

// Round 10
// 106.593 us; speedup vs baseline: 1.4410x; 1.3792x over previous
//
#include <hip/hip_runtime.h>
#include <hip/hip_bf16.h>

#define BB 64
#define TT 16
#define ROWS 1024
#define ADIM 32
#define HID 1536
#define NCAT 4
#define MT_MAX 20            // worst case sum ceil(cnt_c/4) = 19
#define NTILE 24             // HID/64 n-tiles
#define GRID_G (MT_MAX * NTILE)   // 480 = 8 * 60

typedef __attribute__((ext_vector_type(8))) short bf16x8;
typedef __attribute__((ext_vector_type(8))) unsigned short ushort8;
typedef __attribute__((ext_vector_type(4))) float f32x4;

static __device__ __forceinline__ unsigned short fb(float f) {
    return __builtin_bit_cast(unsigned short, __float2bfloat16(f));
}

// ---------------------------------------------------------------------------
// prep: group samples by category into padded 4-sample m-tiles.
// ---------------------------------------------------------------------------
__global__ void prep_kernel(const int* __restrict__ cat_ids,
                            int* __restrict__ msample, int* __restrict__ mcat) {
    __shared__ int counts[NCAT];
    const int t = threadIdx.x;
    if (t < NCAT) {
        int c = 0;
        for (int s = 0; s < BB; ++s) c += (cat_ids[s] == t);
        counts[t] = c;
    }
    __syncthreads();
    if (t < NCAT) {
        int off = 0;
        for (int c = 0; c < t; ++c) off += (counts[c] + 3) >> 2;
        const int mt = (counts[t] + 3) >> 2;
        int idx = 0;
        for (int s = 0; s < BB; ++s)
            if (cat_ids[s] == t) msample[off * 4 + (idx++)] = s;
        for (; idx < mt * 4; ++idx) msample[off * 4 + idx] = -1;
        for (int mm = 0; mm < mt; ++mm) mcat[off + mm] = t;
    }
    __syncthreads();
    if (t == 0) {
        int tot = 0;
        for (int c = 0; c < NCAT; ++c) tot += (counts[c] + 3) >> 2;
        for (int mm = tot; mm < MT_MAX; ++mm) mcat[mm] = -1;
    }
}

// ---------------------------------------------------------------------------
// build_x: X[row][0:1536] = actions @ W1[cat] + b1[cat]; X[row][1536:3072] = PE
// (standard bf16 layout, stride 3072)
// ---------------------------------------------------------------------------
__global__ void build_x_kernel(const float* __restrict__ actions,
                               const int* __restrict__ timesteps,
                               const int* __restrict__ cat_ids,
                               const float* __restrict__ W1,
                               const float* __restrict__ b1,
                               unsigned short* __restrict__ X) {
    const int s = blockIdx.x;
    const int part = blockIdx.y;
    const int t = threadIdx.x;
    if (part < 6) {
        const int cat = cat_ids[s];
        const int h = part * 256 + t;
        __shared__ float act[TT][ADIM];
        const float* ab = actions + (size_t)s * TT * ADIM;
        ((float*)act)[t]       = ab[t];
        ((float*)act)[t + 256] = ab[t + 256];
        __syncthreads();
        const float* W1c = W1 + (size_t)cat * ADIM * HID + h;
        float acc[TT];
        #pragma unroll
        for (int r = 0; r < TT; ++r) acc[r] = 0.f;
        #pragma unroll 8
        for (int d = 0; d < ADIM; ++d) {
            const float wv = W1c[(size_t)d * HID];
            #pragma unroll
            for (int r = 0; r < TT; ++r) acc[r] += act[r][d] * wv;
        }
        const float bias = b1[cat * HID + h];
        #pragma unroll
        for (int r = 0; r < TT; ++r)
            X[(size_t)(s * TT + r) * (2 * HID) + h] = fb(acc[r] + bias);
    } else {
        const float ts = (float)timesteps[s];
        #pragma unroll
        for (int j = 0; j < 6; ++j) {
            const int i = j * 256 + t;
            const int ii = (i < 768) ? i : i - 768;
            const float freq = expf(-9.210340371976184f * (float)ii * (1.0f / 768.0f));
            const float ang = ts * freq;
            const float v = (i < 768) ? sinf(ang) : cosf(ang);
            const unsigned short bv = fb(v);
            for (int r = 0; r < TT; ++r)
                X[(size_t)(s * TT + r) * (2 * HID) + HID + i] = bv;
        }
    }
}

// ---------------------------------------------------------------------------
// convert_w: W[cat][k][n] fp32 -> B'[tile gwid][g][n][e] bf16, where
//   gwid = (cat*24 + nt)*(K/32) + tG, tile = 4KB, element (g,n,e) =
//   bf16(W[cat][tG*32 + g*8 + e][nt*64 + n]).  One wave per tile:
//   32 coalesced 256B row-loads + 4 x 1KB coalesced stores.
// ---------------------------------------------------------------------------
template<int K>
__global__ __launch_bounds__(256) void convert_w(const float* __restrict__ W,
                                                 unsigned short* __restrict__ Bp) {
    constexpr int TK = K / 32;
    const int gwid = blockIdx.x * 4 + (threadIdx.x >> 6);
    const int l = threadIdx.x & 63;
    const int tG = gwid % TK;
    const int rest = gwid / TK;
    const int nt = rest % NTILE;
    const int cat = rest / NTILE;
    const float* src = W + ((size_t)cat * K + (size_t)tG * 32) * HID + nt * 64 + l;
    unsigned short* dst = Bp + (size_t)gwid * 2048 + l * 8;
    #pragma unroll
    for (int g = 0; g < 4; ++g) {
        ushort8 v;
        #pragma unroll
        for (int e = 0; e < 8; ++e) v[e] = fb(src[(size_t)(g * 8 + e) * HID]);
        *(ushort8*)(dst + g * 512) = v;
    }
}

// ---------------------------------------------------------------------------
// gemm_w: 64x64 tile per block, 4 waves, in-block K-split (wave w owns K/4).
//   B: global_load_lds (4 insts/step, zero VGPR dest) into wave-private
//      triple-buffered frag-linear LDS tiles; counted s_waitcnt vmcnt(12)
//      (retires exactly {A(t), B(t)} per step), NO barriers in K-loop.
//   A: bf16 X/H rows -> 3-stage register frags (48 VGPR, literal-indexed).
//   End: round-based cross-wave LDS reduce + fused bias(+swish) store.
// ---------------------------------------------------------------------------
template<int K, bool SWISH, bool BF16OUT>
__global__ __launch_bounds__(256, 2) void gemm_w(
        const unsigned short* __restrict__ Xin,  // [ROWS][K] bf16
        const unsigned short* __restrict__ Bp,   // B' tiles (frag-linear bf16)
        const float* __restrict__ bias,          // [NCAT][HID]
        const int* __restrict__ msample,
        const int* __restrict__ mcat,
        void* __restrict__ Out) {
    constexpr int KP = K / 4;
    constexpr int NTK = KP / 32;
    static_assert(NTK % 3 == 0, "NTK must be divisible by 3");

    // bijective XCD swizzle (480 % 8 == 0), nt-major per XCD (B-panel reuse)
    const int id = blockIdx.x;
    const int gg = (id & 7) * (GRID_G / 8) + (id >> 3);
    const int nt = gg / MT_MAX;
    const int m  = gg - nt * MT_MAX;
    const int cat = mcat[m];
    if (cat < 0) return;
    const int n0 = nt * 64;

    const int q = threadIdx.x, w = q >> 6, l = q & 63;
    const int col = l & 15, g = l >> 4;

    __shared__ unsigned short Bimg[4][3][4][64][8];  // 49,152 B
    __shared__ float Rr[4][16][68];                  // 17,408 B

    int sidx[4];
    #pragma unroll
    for (int f = 0; f < 4; ++f) sidx[f] = msample[m * 4 + f];

    const unsigned short* aB[4];
    #pragma unroll
    for (int mf = 0; mf < 4; ++mf) {
        const int s = sidx[mf] < 0 ? 0 : sidx[mf];
        aB[mf] = Xin + ((size_t)s * TT + col) * K + w * KP + g * 8;
    }
    const unsigned short* bP =
        Bp + ((size_t)(cat * NTILE + nt) * (K / 32) + (size_t)w * NTK) * 2048 + l * 8;

    f32x4 acc[4][4];
    #pragma unroll
    for (int i = 0; i < 4; ++i)
        #pragma unroll
        for (int j = 0; j < 4; ++j) acc[i][j] = f32x4{0.f, 0.f, 0.f, 0.f};

    bf16x8 aS[3][4];   // 3-stage A frags; all indices literal at use sites

#define ISSUE_B(BUF) do { \
    __builtin_amdgcn_global_load_lds((const __attribute__((address_space(1))) unsigned int*)(bP), \
        (__attribute__((address_space(3))) unsigned int*)(&Bimg[w][BUF][0][0][0]), 16, 0, 0); \
    __builtin_amdgcn_global_load_lds((const __attribute__((address_space(1))) unsigned int*)(bP + 512), \
        (__attribute__((address_space(3))) unsigned int*)(&Bimg[w][BUF][1][0][0]), 16, 0, 0); \
    __builtin_amdgcn_global_load_lds((const __attribute__((address_space(1))) unsigned int*)(bP + 1024), \
        (__attribute__((address_space(3))) unsigned int*)(&Bimg[w][BUF][2][0][0]), 16, 0, 0); \
    __builtin_amdgcn_global_load_lds((const __attribute__((address_space(1))) unsigned int*)(bP + 1536), \
        (__attribute__((address_space(3))) unsigned int*)(&Bimg[w][BUF][3][0][0]), 16, 0, 0); \
    bP += 2048; } while (0)

#define LOAD_A(T, ST) do { const int tc_ = ((T) < NTK) ? (T) : NTK - 1; \
    aS[ST][0] = *(const bf16x8*)(aB[0] + tc_ * 32); \
    aS[ST][1] = *(const bf16x8*)(aB[1] + tc_ * 32); \
    aS[ST][2] = *(const bf16x8*)(aB[2] + tc_ * 32); \
    aS[ST][3] = *(const bf16x8*)(aB[3] + tc_ * 32); } while (0)

#define COMPUTE(BUF, ST) do { \
    bf16x8 bf0 = *(const bf16x8*)(&Bimg[w][BUF][g][ 0 + col][0]); \
    bf16x8 bf1 = *(const bf16x8*)(&Bimg[w][BUF][g][16 + col][0]); \
    bf16x8 bf2 = *(const bf16x8*)(&Bimg[w][BUF][g][32 + col][0]); \
    bf16x8 bf3 = *(const bf16x8*)(&Bimg[w][BUF][g][48 + col][0]); \
    acc[0][0] = __builtin_amdgcn_mfma_f32_16x16x32_bf16(aS[ST][0], bf0, acc[0][0], 0, 0, 0); \
    acc[0][1] = __builtin_amdgcn_mfma_f32_16x16x32_bf16(aS[ST][0], bf1, acc[0][1], 0, 0, 0); \
    acc[0][2] = __builtin_amdgcn_mfma_f32_16x16x32_bf16(aS[ST][0], bf2, acc[0][2], 0, 0, 0); \
    acc[0][3] = __builtin_amdgcn_mfma_f32_16x16x32_bf16(aS[ST][0], bf3, acc[0][3], 0, 0, 0); \
    acc[1][0] = __builtin_amdgcn_mfma_f32_16x16x32_bf16(aS[ST][1], bf0, acc[1][0], 0, 0, 0); \
    acc[1][1] = __builtin_amdgcn_mfma_f32_16x16x32_bf16(aS[ST][1], bf1, acc[1][1], 0, 0, 0); \
    acc[1][2] = __builtin_amdgcn_mfma_f32_16x16x32_bf16(aS[ST][1], bf2, acc[1][2], 0, 0, 0); \
    acc[1][3] = __builtin_amdgcn_mfma_f32_16x16x32_bf16(aS[ST][1], bf3, acc[1][3], 0, 0, 0); \
    acc[2][0] = __builtin_amdgcn_mfma_f32_16x16x32_bf16(aS[ST][2], bf0, acc[2][0], 0, 0, 0); \
    acc[2][1] = __builtin_amdgcn_mfma_f32_16x16x32_bf16(aS[ST][2], bf1, acc[2][1], 0, 0, 0); \
    acc[2][2] = __builtin_amdgcn_mfma_f32_16x16x32_bf16(aS[ST][2], bf2, acc[2][2], 0, 0, 0); \
    acc[2][3] = __builtin_amdgcn_mfma_f32_16x16x32_bf16(aS[ST][2], bf3, acc[2][3], 0, 0, 0); \
    acc[3][0] = __builtin_amdgcn_mfma_f32_16x16x32_bf16(aS[ST][3], bf0, acc[3][0], 0, 0, 0); \
    acc[3][1] = __builtin_amdgcn_mfma_f32_16x16x32_bf16(aS[ST][3], bf1, acc[3][1], 0, 0, 0); \
    acc[3][2] = __builtin_amdgcn_mfma_f32_16x16x32_bf16(aS[ST][3], bf2, acc[3][2], 0, 0, 0); \
    acc[3][3] = __builtin_amdgcn_mfma_f32_16x16x32_bf16(aS[ST][3], bf3, acc[3][3], 0, 0, 0); \
    } while (0)

    // prologue: issue order A0 B0 A1 B1 B2 (20 outstanding vmem ops)
    LOAD_A(0, 0); ISSUE_B(0);
    LOAD_A(1, 1); ISSUE_B(1);
    ISSUE_B(2);

    for (int t = 0; t < NTK; t += 3) {
        asm volatile("s_waitcnt vmcnt(12)" ::: "memory");   // retires A(t),B(t)
        COMPUTE(0, 0); LOAD_A(t + 2, 2); ISSUE_B(0);
        asm volatile("s_waitcnt vmcnt(12)" ::: "memory");
        COMPUTE(1, 1); LOAD_A(t + 3, 0); ISSUE_B(1);
        asm volatile("s_waitcnt vmcnt(12)" ::: "memory");
        COMPUTE(2, 2); LOAD_A(t + 4, 1); ISSUE_B(2);
    }

    // -------- round-based cross-wave k-slice reduce --------
    __syncthreads();
    #pragma unroll
    for (int r = 1; r < 4; ++r) {
        const int sdst = (w + r) & 3;
        #pragma unroll
        for (int mf = 0; mf < 4; ++mf) {
            if (mf != sdst) continue;
            #pragma unroll
            for (int nf = 0; nf < 4; ++nf)
                #pragma unroll
                for (int jj = 0; jj < 4; ++jj)
                    Rr[mf][g * 4 + jj][nf * 16 + col] = acc[mf][nf][jj];
        }
        __syncthreads();
        #pragma unroll
        for (int mf = 0; mf < 4; ++mf) {
            if (mf != w) continue;
            #pragma unroll
            for (int nf = 0; nf < 4; ++nf)
                #pragma unroll
                for (int jj = 0; jj < 4; ++jj)
                    acc[mf][nf][jj] += Rr[mf][g * 4 + jj][nf * 16 + col];
        }
        __syncthreads();
    }

    // -------- fused epilogue: bias (+swish), direct store --------
    #pragma unroll
    for (int mf = 0; mf < 4; ++mf) {
        if (mf != w || sidx[mf] < 0) continue;
        const float* bc = bias + (size_t)cat * HID + n0 + col;
        #pragma unroll
        for (int nf = 0; nf < 4; ++nf) {
            const float bv = bc[nf * 16];
            #pragma unroll
            for (int jj = 0; jj < 4; ++jj) {
                float v = acc[mf][nf][jj] + bv;
                if (SWISH) v = v / (1.f + __expf(-v));
                const size_t off = ((size_t)sidx[mf] * TT + g * 4 + jj) * HID
                                 + n0 + nf * 16 + col;
                if (BF16OUT) ((unsigned short*)Out)[off] = fb(v);
                else         ((float*)Out)[off] = v;
            }
        }
    }
#undef ISSUE_B
#undef LOAD_A
#undef COMPUTE
}

// ---------------------------------------------------------------------------
extern "C" void kernel_launch(void* const* d_in, const int* in_sizes, int n_in,
                              void* d_out, int out_size, void* d_ws, size_t ws_size,
                              hipStream_t stream) {
    const float* actions   = (const float*)d_in[0];
    const int*   timesteps = (const int*)d_in[1];
    const int*   cat_ids   = (const int*)d_in[2];
    const float* W1        = (const float*)d_in[3];
    const float* b1        = (const float*)d_in[4];
    const float* W2        = (const float*)d_in[5];
    const float* b2        = (const float*)d_in[6];
    const float* W3        = (const float*)d_in[7];
    const float* b3        = (const float*)d_in[8];

    char* ws = (char*)d_ws;
    int* msample      = (int*)ws;                             // 320 B
    int* mcat         = (int*)(ws + 320);                     // 80 B
    unsigned short* X = (unsigned short*)(ws + 512);          // 6,291,456 B
    unsigned short* H = (unsigned short*)(ws + 512 + 6291456);        // 3,145,728 B
    unsigned short* B2 = (unsigned short*)(ws + 512 + 9437184);       // 37,748,736 B
    unsigned short* B3 = (unsigned short*)(ws + 512 + 47185920);      // 18,874,368 B
    // end @ ~66.06 MB (+12 KB clamped-prefetch overrun slack within ws)

    prep_kernel<<<1, 64, 0, stream>>>(cat_ids, msample, mcat);
    build_x_kernel<<<dim3(BB, 7), 256, 0, stream>>>(actions, timesteps, cat_ids, W1, b1, X);

    convert_w<2 * HID><<<NCAT * NTILE * (2 * HID / 32) / 4, 256, 0, stream>>>(W2, B2);
    gemm_w<2 * HID, true, true><<<GRID_G, 256, 0, stream>>>(
        X, B2, b2, msample, mcat, H);

    convert_w<HID><<<NCAT * NTILE * (HID / 32) / 4, 256, 0, stream>>>(W3, B3);
    gemm_w<HID, false, false><<<GRID_G, 256, 0, stream>>>(
        H, B3, b3, msample, mcat, d_out);
}